// Round 4
// baseline (128.296 us; speedup 1.0000x reference)
//
#include <hip/hip_runtime.h>
#include <hip/hip_bf16.h>
#include <stdint.h>

#define BATCH 8192
#define DIM   512
#define BM    256                     // pair tile: 256x256 of the sim matrix
#define NT    (BATCH / BM)            // 32 tiles per dim
#define NPAIR (NT * (NT + 1) / 2)     // 528 upper-triangle tile pairs
#define NBLK  (NPAIR * 2)             // 1056 blocks: 128x256 half-pairs

// Fb = F_norm * sqrt(log2(e)/T) so acc = Fb·Fbᵀ is already log2-domain logits.
#define FEAT_SCALE 4.5398164f         // sqrt(1.4426950409/0.07)
#define LN2        0.69314718055994531f

typedef __attribute__((ext_vector_type(8))) short short8;
typedef __attribute__((ext_vector_type(4))) float f32x4;

__device__ __forceinline__ void gld_lds16(const void* g, void* l) {
  __builtin_amdgcn_global_load_lds(
      (__attribute__((address_space(1))) void*)(uintptr_t)g,
      (__attribute__((address_space(3))) void*)(uintptr_t)l,
      16, 0, 0);
}

// ---------------------------------------------------------------------------
// Kernel 1: row-normalize fp32 -> bf16 * FEAT_SCALE. One wave per row.
// ---------------------------------------------------------------------------
__global__ __launch_bounds__(256) void normalize_bf16(
    const float* __restrict__ x, __hip_bfloat16* __restrict__ o,
    float* __restrict__ rowsum) {
  const int wv = threadIdx.x >> 6, lane = threadIdx.x & 63;
  const int row = blockIdx.x * 4 + wv;
  if (lane == 0) rowsum[row] = 0.0f;
  const float4* xr = (const float4*)(x + (size_t)row * DIM);
  const float4 v0 = xr[lane];
  const float4 v1 = xr[lane + 64];
  float ss = v0.x * v0.x + v0.y * v0.y + v0.z * v0.z + v0.w * v0.w +
             v1.x * v1.x + v1.y * v1.y + v1.z * v1.z + v1.w * v1.w;
#pragma unroll
  for (int m = 32; m > 0; m >>= 1) ss += __shfl_xor(ss, m, 64);
  const float inv = FEAT_SCALE / fmaxf(sqrtf(ss), 1e-12f);
  ushort4 p0, p1;
  p0.x = __bfloat16_as_ushort(__float2bfloat16(v0.x * inv));
  p0.y = __bfloat16_as_ushort(__float2bfloat16(v0.y * inv));
  p0.z = __bfloat16_as_ushort(__float2bfloat16(v0.z * inv));
  p0.w = __bfloat16_as_ushort(__float2bfloat16(v0.w * inv));
  p1.x = __bfloat16_as_ushort(__float2bfloat16(v1.x * inv));
  p1.y = __bfloat16_as_ushort(__float2bfloat16(v1.y * inv));
  p1.z = __bfloat16_as_ushort(__float2bfloat16(v1.z * inv));
  p1.w = __bfloat16_as_ushort(__float2bfloat16(v1.w * inv));
  ushort4* orow = (ushort4*)(o + (size_t)row * DIM);
  orow[lane]      = p0;
  orow[lane + 64] = p1;
}

// ---------------------------------------------------------------------------
// Kernel 2: 1056 blocks; block = 128 rows x 256 cols (half of an upper-
// triangle 256x256 tile-pair; full K) -> 1.21x makespan tax vs 1.46x at 528.
// 8 waves as 2M(64r) x 4N(64c), acc[4][4].
//
// LDS: TRIPLE-buffered planes: A[p] = [128][64] bf16 (16 KB) at p*16K;
// B[p] = [256][64] (32 KB) at 48K + p*32K; total 144 KB + 1 KB colAcc.
// Tile T uses plane T%3; stages for T+2 (plane (T+2)%3) issued during T
// never collide with reads of T or T+1.
//
// m201 phase discipline (T3+T4): per tile two phases (k-slice 0/1), each
// {8 ds_read_b128 frags; 3 gld_lds stage calls; [vmcnt(6) at 2nd phase
// only]; s_barrier; lgkmcnt(0); setprio(1); 16 MFMA; setprio(0); s_barrier}.
// vmcnt induction: at ph(T,1) in-flight <= {T+1:6, T+2:6}; vmcnt(6) retires
// tile T+1 exactly, before the barrier that precedes its reads. Never 0 in
// the main loop; wrap stages (tiles 8,9 -> 0,1's data, dead planes) keep
// counts uniform. Swizzle: 16B chunk ^= (row&7) on both gld source and
// ds_read (verified: 3.5M -> 270K conflicts).
// ---------------------------------------------------------------------------
__global__ __launch_bounds__(512, 2) void sim_lse_kernel(
    const __hip_bfloat16* __restrict__ F, float* __restrict__ rowsum,
    float* __restrict__ possim) {
  extern __shared__ char smem[];
  float* colAcc = (float*)(smem + 147456);

  const int t  = blockIdx.x;
  const int pr = t >> 1;          // pair index 0..527
  const int hb = t & 1;           // which 128-row half
  int by = (int)((65.0f - sqrtf(65.0f * 65.0f - 8.0f * (float)pr)) * 0.5f);
  if (by > NT - 1) by = NT - 1;
  if (by < 0) by = 0;
  while ((by + 1) * (65 - (by + 1)) / 2 <= pr) ++by;
  while (by * (65 - by) / 2 > pr) --by;
  const int bx = by + (pr - by * (65 - by) / 2);
  const bool diagTile = (bx == by);
  const bool hasPos = (bx == by + NT / 2);

  const int rowB = by * BM + hb * 128;   // 128 rows
  const int colB = bx * BM;              // 256 cols

  const int tid  = threadIdx.x;
  const int lane = tid & 63;
  const int wv   = tid >> 6;
  const int q    = lane >> 4;
  const int l15  = lane & 15;
  const int waveM = wv >> 2;   // 0..1 -> 64-row half
  const int waveN = wv & 3;    // 0..3 -> 64-col quarter

  // staging source: thread t covers (row r0 = t>>3, chunk t&7), chunk
  // pre-swizzled ^(r0&7); call h adds h*64 rows.
  const int r0 = tid >> 3, c0 = tid & 7;
  const int csrc = c0 ^ (r0 & 7);
  const __hip_bfloat16* gAp = F + (size_t)(rowB + r0) * DIM + csrc * 8;
  const __hip_bfloat16* gBp = F + (size_t)(colB + r0) * DIM + csrc * 8;

#define STAGE_FH(Tn) do {                                                     \
    const int ko_ = ((Tn) & 7) * 64;                                          \
    const int pA_ = ((Tn) % 3) * 16384;                                       \
    const int pB_ = 49152 + ((Tn) % 3) * 32768;                               \
    gld_lds16(gAp + ko_,             smem + pA_ + wv * 1024);                 \
    gld_lds16(gAp + ko_ + 64 * DIM,  smem + pA_ + 8192 + wv * 1024);          \
    gld_lds16(gBp + ko_,             smem + pB_ + wv * 1024);                 \
  } while (0)
#define STAGE_SH(Tn) do {                                                     \
    const int ko_ = ((Tn) & 7) * 64;                                          \
    const int pB_ = 49152 + ((Tn) % 3) * 32768;                               \
    gld_lds16(gBp + ko_ + 64 * DIM,  smem + pB_ + 8192 + wv * 1024);          \
    gld_lds16(gBp + ko_ + 128 * DIM, smem + pB_ + 16384 + wv * 1024);         \
    gld_lds16(gBp + ko_ + 192 * DIM, smem + pB_ + 24576 + wv * 1024);         \
  } while (0)

  // fragment reads: row r at byte r*128 + ((q_or_q4 ^ (r&7))*16); r&7==l15&7
  const int cs0 = ((q)     ^ (l15 & 7)) * 16;   // k 0..31
  const int cs1 = ((4 + q) ^ (l15 & 7)) * 16;   // k 32..63
  const int arow = waveM * 8192 + l15 * 128;    // A: row = waveM*64+m*16+l15
  const int brow = waveN * 8192 + l15 * 128;    // B: row = waveN*64+n*16+l15

  short8 a[4], b[4];
  f32x4 acc[4][4] = {};

#define RD(PL_, CS_) do {                                                     \
    const char* pa_ = smem + (PL_) * 16384 + arow + (CS_);                    \
    a[0] = *(const short8*)(pa_);                                             \
    a[1] = *(const short8*)(pa_ + 2048);                                      \
    a[2] = *(const short8*)(pa_ + 4096);                                      \
    a[3] = *(const short8*)(pa_ + 6144);                                      \
    const char* pb_ = smem + 49152 + (PL_) * 32768 + brow + (CS_);            \
    b[0] = *(const short8*)(pb_);                                             \
    b[1] = *(const short8*)(pb_ + 2048);                                      \
    b[2] = *(const short8*)(pb_ + 4096);                                      \
    b[3] = *(const short8*)(pb_ + 6144);                                      \
  } while (0)
#define MFMA16() do {                                                         \
    __builtin_amdgcn_s_setprio(1);                                            \
    _Pragma("unroll")                                                         \
    for (int m_ = 0; m_ < 4; ++m_)                                            \
      _Pragma("unroll")                                                       \
      for (int n_ = 0; n_ < 4; ++n_)                                          \
        acc[m_][n_] = __builtin_amdgcn_mfma_f32_16x16x32_bf16(                \
            a[m_], b[n_], acc[m_][n_], 0, 0, 0);                              \
    __builtin_amdgcn_s_setprio(0);                                            \
  } while (0)

  if (tid < 256) colAcc[tid] = 0.0f;

  // prologue: stage tiles 0 and 1 (12 calls); vmcnt(6) retires tile 0,
  // leaves tile 1's 6 in flight = steady-state entry condition.
  STAGE_FH(0); STAGE_SH(0); STAGE_FH(1); STAGE_SH(1);
  asm volatile("s_waitcnt vmcnt(6)" ::: "memory");
  __builtin_amdgcn_s_barrier();

#pragma unroll
  for (int T = 0; T < 8; ++T) {
    const int pl = T % 3;
    // phase (T, ks0)
    RD(pl, cs0);
    STAGE_FH(T + 2);
    __builtin_amdgcn_s_barrier();
    asm volatile("s_waitcnt lgkmcnt(0)" ::: "memory");
    MFMA16();
    __builtin_amdgcn_s_barrier();
    // phase (T, ks1)
    RD(pl, cs1);
    STAGE_SH(T + 2);
    asm volatile("s_waitcnt vmcnt(6)" ::: "memory");   // retire tile T+1
    __builtin_amdgcn_s_barrier();
    asm volatile("s_waitcnt lgkmcnt(0)" ::: "memory");
    MFMA16();
    __builtin_amdgcn_s_barrier();
  }

  // drain wrap-prefetches before reusing staging LDS as reduction buffer
  asm volatile("s_waitcnt vmcnt(0)" ::: "memory");
  __builtin_amdgcn_s_barrier();

  // --- epilogue: exp2 (log2-domain acc), row/col partial sums ---
  float* redBuf = (float*)smem;   // [64 slots (waveN,l15)][pitch 132] fp32
  float cp[4] = {0.f, 0.f, 0.f, 0.f};
  f32x4 rp[4];

#pragma unroll
  for (int mi = 0; mi < 4; ++mi) {
    f32x4 r = {0.f, 0.f, 0.f, 0.f};
#pragma unroll
    for (int ni = 0; ni < 4; ++ni) {
      const int lc = waveN * 64 + ni * 16 + l15;           // 0..255
#pragma unroll
      for (int rr = 0; rr < 4; ++rr) {
        const int lr = waveM * 64 + mi * 16 + q * 4 + rr;  // 0..127
        const float s = acc[mi][ni][rr];
        float e = exp2f(s);
        if (diagTile && lc == hb * 128 + lr) e = 0.0f;     // exclude self
        r[rr] += e;
        cp[ni] += e;
        if (hasPos && lc == hb * 128 + lr) {
          possim[rowB + lr] = s;
          possim[rowB + lr + BATCH / 2] = s;
        }
      }
    }
    rp[mi] = r;
  }

  {  // transpose-store per-lane row partials (pitch 132 dw = 528 B, 16B ok)
    float* wb = redBuf + (waveN * 16 + l15) * 132 + waveM * 64 + q * 4;
#pragma unroll
    for (int mi = 0; mi < 4; ++mi) *(f32x4*)(wb + mi * 16) = rp[mi];
  }

  if (!diagTile) {  // column credit (symmetry): reduce quads, LDS atomic
#pragma unroll
    for (int ni = 0; ni < 4; ++ni) {
      float c = cp[ni];
      c += __shfl_xor(c, 16, 64);
      c += __shfl_xor(c, 32, 64);
      if (q == 0) atomicAdd(&colAcc[waveN * 64 + ni * 16 + l15], c);
    }
  }
  asm volatile("s_waitcnt lgkmcnt(0)" ::: "memory");
  __builtin_amdgcn_s_barrier();

  {  // 512 threads: 4 threads per row, each sums 16 of 64 partial slots
    const int row = tid >> 2, g = tid & 3;
    float s = 0.f;
#pragma unroll
    for (int j = 0; j < 16; ++j) s += redBuf[(g * 16 + j) * 132 + row];
    s += __shfl_xor(s, 1, 64);
    s += __shfl_xor(s, 2, 64);
    if (g == 0) atomicAdd(&rowsum[rowB + row], s);
  }
  if (!diagTile && tid < 256)
    atomicAdd(&rowsum[colB + tid], colAcc[tid]);
}

// ---------------------------------------------------------------------------
// Kernel 3: loss = mean_i( log(rowsum_i) - possim_i * ln2 )
// ---------------------------------------------------------------------------
__global__ __launch_bounds__(1024) void finalize_kernel(
    const float* __restrict__ rowsum, const float* __restrict__ possim,
    float* __restrict__ out) {
  float acc = 0.0f;
  for (int i = threadIdx.x; i < BATCH; i += 1024)
    acc += __logf(rowsum[i]) - possim[i] * LN2;
#pragma unroll
  for (int m = 32; m > 0; m >>= 1) acc += __shfl_xor(acc, m, 64);
  __shared__ float ws[16];
  const int lane = threadIdx.x & 63, wv = threadIdx.x >> 6;
  if (lane == 0) ws[wv] = acc;
  __syncthreads();
  if (threadIdx.x == 0) {
    float tot = 0.0f;
#pragma unroll
    for (int k = 0; k < 16; ++k) tot += ws[k];
    out[0] = tot * (1.0f / (float)BATCH);
  }
}

extern "C" void kernel_launch(void* const* d_in, const int* in_sizes, int n_in,
                              void* d_out, int out_size, void* d_ws, size_t ws_size,
                              hipStream_t stream) {
  const float* x = (const float*)d_in[0];
  float* out = (float*)d_out;

  __hip_bfloat16* Fb = (__hip_bfloat16*)d_ws;
  float* rowsum = (float*)((char*)d_ws + (size_t)BATCH * DIM * sizeof(__hip_bfloat16));
  float* possim = rowsum + BATCH;

  static bool attr_done = false;
  if (!attr_done) {
    (void)hipFuncSetAttribute(reinterpret_cast<const void*>(sim_lse_kernel),
                              hipFuncAttributeMaxDynamicSharedMemorySize, 148480);
    attr_done = true;
  }

  normalize_bf16<<<BATCH / 4, 256, 0, stream>>>(x, Fb, rowsum);
  sim_lse_kernel<<<NBLK, 512, 148480, stream>>>(Fb, rowsum, possim);
  finalize_kernel<<<1, 1024, 0, stream>>>(rowsum, possim, out);
}

// Round 5
// 117.579 us; speedup vs baseline: 1.0911x; 1.0911x over previous
//
#include <hip/hip_runtime.h>
#include <hip/hip_bf16.h>
#include <stdint.h>

#define BATCH 8192
#define DIM   512
#define BM    256                     // pair tile: 256x256 of the sim matrix
#define NT    (BATCH / BM)            // 32 tiles per dim
#define NPAIR (NT * (NT + 1) / 2)     // 528 upper-triangle tile pairs
#define NBLK  (NPAIR * 2)             // 1056 blocks: 128x256 half-pairs

// Fb = F_norm * sqrt(log2(e)/T) so acc = Fb·Fbᵀ is already log2-domain logits.
#define FEAT_SCALE 4.5398164f         // sqrt(1.4426950409/0.07)
#define LN2        0.69314718055994531f

typedef __attribute__((ext_vector_type(8))) short short8;
typedef __attribute__((ext_vector_type(4))) float f32x4;

__device__ __forceinline__ void gld_lds16(const void* g, void* l) {
  __builtin_amdgcn_global_load_lds(
      (__attribute__((address_space(1))) void*)(uintptr_t)g,
      (__attribute__((address_space(3))) void*)(uintptr_t)l,
      16, 0, 0);
}

// ---------------------------------------------------------------------------
// Kernel 1: row-normalize fp32 -> bf16 * FEAT_SCALE. One wave per row.
// ---------------------------------------------------------------------------
__global__ __launch_bounds__(256) void normalize_bf16(
    const float* __restrict__ x, __hip_bfloat16* __restrict__ o,
    float* __restrict__ rowsum) {
  const int wv = threadIdx.x >> 6, lane = threadIdx.x & 63;
  const int row = blockIdx.x * 4 + wv;
  if (lane == 0) rowsum[row] = 0.0f;
  const float4* xr = (const float4*)(x + (size_t)row * DIM);
  const float4 v0 = xr[lane];
  const float4 v1 = xr[lane + 64];
  float ss = v0.x * v0.x + v0.y * v0.y + v0.z * v0.z + v0.w * v0.w +
             v1.x * v1.x + v1.y * v1.y + v1.z * v1.z + v1.w * v1.w;
#pragma unroll
  for (int m = 32; m > 0; m >>= 1) ss += __shfl_xor(ss, m, 64);
  const float inv = FEAT_SCALE / fmaxf(sqrtf(ss), 1e-12f);
  ushort4 p0, p1;
  p0.x = __bfloat16_as_ushort(__float2bfloat16(v0.x * inv));
  p0.y = __bfloat16_as_ushort(__float2bfloat16(v0.y * inv));
  p0.z = __bfloat16_as_ushort(__float2bfloat16(v0.z * inv));
  p0.w = __bfloat16_as_ushort(__float2bfloat16(v0.w * inv));
  p1.x = __bfloat16_as_ushort(__float2bfloat16(v1.x * inv));
  p1.y = __bfloat16_as_ushort(__float2bfloat16(v1.y * inv));
  p1.z = __bfloat16_as_ushort(__float2bfloat16(v1.z * inv));
  p1.w = __bfloat16_as_ushort(__float2bfloat16(v1.w * inv));
  ushort4* orow = (ushort4*)(o + (size_t)row * DIM);
  orow[lane]      = p0;
  orow[lane + 64] = p1;
}

// ---------------------------------------------------------------------------
// Kernel 2: 1056 blocks; block = 128 rows x 256 cols (half of an upper-
// triangle 256x256 tile-pair, full K). 4 waves, wave = ALL 128 rows x 64
// cols (acc[8][4]): B-frags read once per k-slice, reused across both
// M-halves -> 375 B LDS read per MFMA (vs 512 at 64x64 wave tile).
//
// R0-proven sync skeleton: single-buffer LDS (A[128][64] 16 KB + B[256][64]
// 32 KB = 48 KB static), per K-step {stage 12 gld_lds calls; __syncthreads;
// ds_read frags + 64 MFMA/wave; __syncthreads}. Multi-block co-residency
// (2-3 blocks/CU) hides the barrier drain (the mechanism that made R0 win).
// Swizzle: 16B chunk ^= (row&7) on BOTH gld source and ds_read (verified).
// ---------------------------------------------------------------------------
__global__ __launch_bounds__(256, 2) void sim_lse_kernel(
    const __hip_bfloat16* __restrict__ F, float* __restrict__ rowsum,
    float* __restrict__ possim) {
  __shared__ char smem[49152];

  const int t  = blockIdx.x;
  const int pr = t >> 1;          // pair index 0..527
  const int hb = t & 1;           // which 128-row half of the pair
  int by = (int)((65.0f - sqrtf(65.0f * 65.0f - 8.0f * (float)pr)) * 0.5f);
  if (by > NT - 1) by = NT - 1;
  if (by < 0) by = 0;
  while ((by + 1) * (65 - (by + 1)) / 2 <= pr) ++by;
  while (by * (65 - by) / 2 > pr) --by;
  const int bx = by + (pr - by * (65 - by) / 2);
  const bool diagTile = (bx == by);
  const bool hasPos = (bx == by + NT / 2);

  const int rowB = by * BM + hb * 128;   // 128 rows
  const int colB = bx * BM;              // 256 cols

  const int tid  = threadIdx.x;
  const int lane = tid & 63;
  const int wv   = tid >> 6;      // wave = col quarter (64 cols), all 128 rows
  const int q    = lane >> 4;
  const int l15  = lane & 15;

  // staging source: thread t covers (row r0 = t>>3, chunk t&7), chunk
  // pre-swizzled ^(r0&7); call h adds h*32 rows (32 = 0 mod 8, swizzle-safe).
  const int r0 = tid >> 3, c0 = tid & 7;
  const int csrc = c0 ^ (r0 & 7);
  const __hip_bfloat16* gA = F + (size_t)(rowB + r0) * DIM + csrc * 8;
  const __hip_bfloat16* gB = F + (size_t)(colB + r0) * DIM + csrc * 8;

  // A plane at 0 (row r -> r*128), B plane at 16384 (row r -> 16384+r*128)
#define STAGE(T_) do {                                                        \
    const int ko_ = (T_) * 64;                                                \
    gld_lds16(gA + ko_,                smem + wv * 1024);                     \
    gld_lds16(gA + ko_ + 32 * DIM,     smem + 4096 + wv * 1024);              \
    gld_lds16(gA + ko_ + 64 * DIM,     smem + 8192 + wv * 1024);              \
    gld_lds16(gA + ko_ + 96 * DIM,     smem + 12288 + wv * 1024);             \
    gld_lds16(gB + ko_,                smem + 16384 + wv * 1024);             \
    gld_lds16(gB + ko_ + 32 * DIM,     smem + 20480 + wv * 1024);             \
    gld_lds16(gB + ko_ + 64 * DIM,     smem + 24576 + wv * 1024);             \
    gld_lds16(gB + ko_ + 96 * DIM,     smem + 28672 + wv * 1024);             \
    gld_lds16(gB + ko_ + 128 * DIM,    smem + 32768 + wv * 1024);             \
    gld_lds16(gB + ko_ + 160 * DIM,    smem + 36864 + wv * 1024);             \
    gld_lds16(gB + ko_ + 192 * DIM,    smem + 40960 + wv * 1024);             \
    gld_lds16(gB + ko_ + 224 * DIM,    smem + 45056 + wv * 1024);             \
  } while (0)

  // fragment reads: row r at byte r*128 + ((kchunk ^ (r&7))*16); r&7==l15&7
  const int cs0 = ((q)     ^ (l15 & 7)) * 16;   // k 0..31
  const int cs1 = ((4 + q) ^ (l15 & 7)) * 16;   // k 32..63
  const int arow = l15 * 128;                        // + H*8192 + mi*2048
  const int brow = 16384 + (wv * 64 + l15) * 128;    // + ni*2048

  short8 a[4], b[4];
  f32x4 acc[8][4] = {};

  for (int T = 0; T < 8; ++T) {
    STAGE(T);
    __syncthreads();
#pragma unroll
    for (int ks = 0; ks < 2; ++ks) {
      const int cs = ks ? cs1 : cs0;
#pragma unroll
      for (int ni = 0; ni < 4; ++ni)
        b[ni] = *(const short8*)(smem + brow + ni * 2048 + cs);
#pragma unroll
      for (int H = 0; H < 2; ++H) {
#pragma unroll
        for (int mi = 0; mi < 4; ++mi)
          a[mi] = *(const short8*)(smem + arow + H * 8192 + mi * 2048 + cs);
#pragma unroll
        for (int mi = 0; mi < 4; ++mi)
#pragma unroll
          for (int ni = 0; ni < 4; ++ni)
            acc[H * 4 + mi][ni] = __builtin_amdgcn_mfma_f32_16x16x32_bf16(
                a[mi], b[ni], acc[H * 4 + mi][ni], 0, 0, 0);
      }
    }
    __syncthreads();
  }

  // --- epilogue: exp2 (log2-domain acc), row/col partial sums ---
  float* redBuf = (float*)smem;   // [64 slots (wv,l15)][pitch 132] fp32
  float cp[4] = {0.f, 0.f, 0.f, 0.f};
  f32x4 rp[8];

#pragma unroll
  for (int mi = 0; mi < 8; ++mi) {
    f32x4 r = {0.f, 0.f, 0.f, 0.f};
#pragma unroll
    for (int ni = 0; ni < 4; ++ni) {
      const int lc = wv * 64 + ni * 16 + l15;       // 0..255
#pragma unroll
      for (int rr = 0; rr < 4; ++rr) {
        const int lr = mi * 16 + q * 4 + rr;        // 0..127
        const float s = acc[mi][ni][rr];
        float e = exp2f(s);
        if (diagTile && lc == hb * 128 + lr) e = 0.0f;   // exclude self
        r[rr] += e;
        cp[ni] += e;
        if (hasPos && lc == hb * 128 + lr) {
          possim[rowB + lr] = s;
          possim[rowB + lr + BATCH / 2] = s;
        }
      }
    }
    rp[mi] = r;
  }

  {  // transpose-store per-lane row partials (pitch 132 dw = 528 B, 16B ok)
    float* wb = redBuf + (wv * 16 + l15) * 132 + q * 4;
#pragma unroll
    for (int mi = 0; mi < 8; ++mi) *(f32x4*)(wb + mi * 16) = rp[mi];
  }

  if (!diagTile) {  // column credit: each wave owns distinct cols -> direct
#pragma unroll
    for (int ni = 0; ni < 4; ++ni) {
      float c = cp[ni];
      c += __shfl_xor(c, 16, 64);
      c += __shfl_xor(c, 32, 64);
      if (q == 0) atomicAdd(&rowsum[colB + wv * 64 + ni * 16 + l15], c);
    }
  }
  __syncthreads();

  {  // 256 threads: 2 threads per row, each sums 32 of 64 partial slots
    const int row = tid >> 1, half = tid & 1;
    const float* bp = redBuf + half * 32 * 132 + row;
    float ssum = 0.f;
#pragma unroll
    for (int j = 0; j < 32; ++j) ssum += bp[j * 132];
    ssum += __shfl_xor(ssum, 1, 64);
    if (half == 0) atomicAdd(&rowsum[rowB + row], ssum);
  }
}

// ---------------------------------------------------------------------------
// Kernel 3: loss = mean_i( log(rowsum_i) - possim_i * ln2 )
// ---------------------------------------------------------------------------
__global__ __launch_bounds__(1024) void finalize_kernel(
    const float* __restrict__ rowsum, const float* __restrict__ possim,
    float* __restrict__ out) {
  float acc = 0.0f;
  for (int i = threadIdx.x; i < BATCH; i += 1024)
    acc += __logf(rowsum[i]) - possim[i] * LN2;
#pragma unroll
  for (int m = 32; m > 0; m >>= 1) acc += __shfl_xor(acc, m, 64);
  __shared__ float ws[16];
  const int lane = threadIdx.x & 63, wv = threadIdx.x >> 6;
  if (lane == 0) ws[wv] = acc;
  __syncthreads();
  if (threadIdx.x == 0) {
    float tot = 0.0f;
#pragma unroll
    for (int k = 0; k < 16; ++k) tot += ws[k];
    out[0] = tot * (1.0f / (float)BATCH);
  }
}

extern "C" void kernel_launch(void* const* d_in, const int* in_sizes, int n_in,
                              void* d_out, int out_size, void* d_ws, size_t ws_size,
                              hipStream_t stream) {
  const float* x = (const float*)d_in[0];
  float* out = (float*)d_out;

  __hip_bfloat16* Fb = (__hip_bfloat16*)d_ws;
  float* rowsum = (float*)((char*)d_ws + (size_t)BATCH * DIM * sizeof(__hip_bfloat16));
  float* possim = rowsum + BATCH;

  normalize_bf16<<<BATCH / 4, 256, 0, stream>>>(x, Fb, rowsum);
  sim_lse_kernel<<<NBLK, 256, 0, stream>>>(Fb, rowsum, possim);
  finalize_kernel<<<1, 1024, 0, stream>>>(rowsum, possim, out);
}